// Round 2
// baseline (754.921 us; speedup 1.0000x reference)
//
#include <hip/hip_runtime.h>

#define NPTS 65536
#define INC  256
#define MID  64
#define KNB  16
#define WSTR 72   // padded LDS row stride (shorts)

typedef __attribute__((ext_vector_type(8))) short short8;
typedef __attribute__((ext_vector_type(4))) float f32x4;

#define MFMA(a, b, c) __builtin_amdgcn_mfma_f32_16x16x32_bf16((a), (b), (c), 0, 0, 0)

__device__ inline short f2bf(float f) {
    unsigned int u = __builtin_bit_cast(unsigned int, f);
    unsigned int r = (u + 0x7fffu + ((u >> 16) & 1u)) >> 16;
    return (short)r;
}
__device__ inline float bf2f(short s) {
    unsigned int u = ((unsigned int)(unsigned short)s) << 16;
    return __builtin_bit_cast(float, u);
}
__device__ inline short8 cvtf8(f32x4 a, f32x4 b) {
    short8 r;
    r[0] = f2bf(a[0]); r[1] = f2bf(a[1]); r[2] = f2bf(a[2]); r[3] = f2bf(a[3]);
    r[4] = f2bf(b[0]); r[5] = f2bf(b[1]); r[6] = f2bf(b[2]); r[7] = f2bf(b[3]);
    return r;
}
__device__ inline short8 load_cvt8(const float* __restrict__ p) {
    const f32x4* v = (const f32x4*)p;
    f32x4 a = v[0], b = v[1];
    return cvtf8(a, b);
}

// ---------------------------------------------------------------------------
// Kernel 1: xx = feats @ w_in.T ; q/k/v = xx @ w_{q,k,v}.T + b
// one wave = 32 rows (2 row-tiles); block = 4 waves = 128 rows; grid = 512
// w_q/w_k/w_v B-fragments register-resident (amortized over both tiles)
// ---------------------------------------------------------------------------
__global__ __launch_bounds__(256) void k_qkv(
    const float* __restrict__ feats, const float* __restrict__ w_in,
    const float* __restrict__ w_q, const float* __restrict__ b_q,
    const float* __restrict__ w_k, const float* __restrict__ b_k,
    const float* __restrict__ w_v, const float* __restrict__ b_v,
    float* __restrict__ q_out, short* __restrict__ k_out, short* __restrict__ v_out)
{
    __shared__ __align__(16) short XL[4][16 * WSTR];
    const int wave = threadIdx.x >> 6, lane = threadIdx.x & 63;
    const int l15 = lane & 15, quad = lane >> 4;
    const int rb0 = (blockIdx.x * 4 + wave) * 32;

    // resident B fragments for the three 64x64 projections
    short8 Bq[2][4], Bk[2][4], Bv[2][4];
    #pragma unroll
    for (int ks = 0; ks < 2; ks++)
        #pragma unroll
        for (int nt = 0; nt < 4; nt++) {
            Bq[ks][nt] = load_cvt8(w_q + (size_t)(nt * 16 + l15) * MID + ks * 32 + quad * 8);
            Bk[ks][nt] = load_cvt8(w_k + (size_t)(nt * 16 + l15) * MID + ks * 32 + quad * 8);
            Bv[ks][nt] = load_cvt8(w_v + (size_t)(nt * 16 + l15) * MID + ks * 32 + quad * 8);
        }
    float bq = b_q[lane & 63], bk = b_k[lane], bv = b_v[lane]; // lane = channel? no: bias per nt below
    (void)bq; (void)bk; (void)bv;

    #pragma unroll
    for (int rt = 0; rt < 2; rt++) {
        const int rb = rb0 + rt * 16;
        f32x4 acc[4];
        #pragma unroll
        for (int nt = 0; nt < 4; nt++) acc[nt] = (f32x4){0.f, 0.f, 0.f, 0.f};

        const float* arow = feats + (size_t)(rb + l15) * INC + quad * 8;
        #pragma unroll
        for (int ks = 0; ks < 8; ks++) {
            short8 a = load_cvt8(arow + ks * 32);
            #pragma unroll
            for (int nt = 0; nt < 4; nt++) {
                short8 b = load_cvt8(w_in + (size_t)(nt * 16 + l15) * INC + ks * 32 + quad * 8);
                acc[nt] = MFMA(a, b, acc[nt]);
            }
        }
        #pragma unroll
        for (int nt = 0; nt < 4; nt++)
            #pragma unroll
            for (int r = 0; r < 4; r++)
                XL[wave][(quad * 4 + r) * WSTR + nt * 16 + l15] = f2bf(acc[nt][r]);

        short8 a0 = *(const short8*)&XL[wave][l15 * WSTR + quad * 8];
        short8 a1 = *(const short8*)&XL[wave][l15 * WSTR + 32 + quad * 8];

        #pragma unroll
        for (int nt = 0; nt < 4; nt++) {
            f32x4 c = (f32x4){0.f, 0.f, 0.f, 0.f};
            c = MFMA(a0, Bq[0][nt], c); c = MFMA(a1, Bq[1][nt], c);
            float bias = b_q[nt * 16 + l15];
            #pragma unroll
            for (int r = 0; r < 4; r++)
                q_out[(size_t)(rb + quad * 4 + r) * MID + nt * 16 + l15] = c[r] + bias;
        }
        #pragma unroll
        for (int nt = 0; nt < 4; nt++) {
            f32x4 c = (f32x4){0.f, 0.f, 0.f, 0.f};
            c = MFMA(a0, Bk[0][nt], c); c = MFMA(a1, Bk[1][nt], c);
            float bias = b_k[nt * 16 + l15];
            #pragma unroll
            for (int r = 0; r < 4; r++)
                k_out[(size_t)(rb + quad * 4 + r) * MID + nt * 16 + l15] = f2bf(c[r] + bias);
        }
        #pragma unroll
        for (int nt = 0; nt < 4; nt++) {
            f32x4 c = (f32x4){0.f, 0.f, 0.f, 0.f};
            c = MFMA(a0, Bv[0][nt], c); c = MFMA(a1, Bv[1][nt], c);
            float bias = b_v[nt * 16 + l15];
            #pragma unroll
            for (int r = 0; r < 4; r++)
                v_out[(size_t)(rb + quad * 4 + r) * MID + nt * 16 + l15] = f2bf(c[r] + bias);
        }
    }
}

// ---------------------------------------------------------------------------
// Kernel 2: per-point attention. one wave = 4 points (64 rows); block = 16 pts.
// grid = 4096. All LDS wave-private -> no __syncthreads.
// ---------------------------------------------------------------------------
__global__ __launch_bounds__(256) void k_attn(
    const float* __restrict__ pos, const int* __restrict__ idx,
    const float* __restrict__ q_ws, const short* __restrict__ k_bf, const short* __restrict__ v_bf,
    const float* __restrict__ pe_w1, const float* __restrict__ pe_b1,
    const float* __restrict__ pe_g1, const float* __restrict__ pe_be1,
    const float* __restrict__ pe_m1, const float* __restrict__ pe_v1,
    const float* __restrict__ pe_w2, const float* __restrict__ pe_b2,
    const float* __restrict__ pe_g2, const float* __restrict__ pe_be2,
    const float* __restrict__ pe_m2, const float* __restrict__ pe_v2,
    const float* __restrict__ ga_w1, const float* __restrict__ ga_b1,
    const float* __restrict__ ga_g1, const float* __restrict__ ga_be1,
    const float* __restrict__ ga_m1, const float* __restrict__ ga_v1,
    const float* __restrict__ ga_w2, const float* __restrict__ ga_b2,
    const float* __restrict__ ga_g2, const float* __restrict__ ga_be2,
    const float* __restrict__ ga_m2, const float* __restrict__ ga_v2,
    short* __restrict__ om_bf)
{
    __shared__ __align__(16) short Wb[4][64 * WSTR];  // 36864 B
    __shared__ float PS[4][64 * 4];                   // PE1 outputs per neighbor (4096 B)
    __shared__ int   JI[4][64];                       // neighbor indices (1024 B)

    const int wave = threadIdx.x >> 6, lane = threadIdx.x & 63;
    const int l15 = lane & 15, quad = lane >> 4;
    const int n0 = (blockIdx.x * 4 + wave) * 4;       // first of 4 points

    // --- stage: one neighbor per lane; idx + pos_enc layer 1 (3 ch) ---
    {
        int m = idx[(size_t)n0 * KNB + lane];
        JI[wave][lane] = m;
        float px = pos[(size_t)m * 3 + 0];
        float py = pos[(size_t)m * 3 + 1];
        float pz = pos[(size_t)m * 3 + 2];
        #pragma unroll
        for (int c = 0; c < 3; c++) {
            float s  = pe_g1[c] * rsqrtf(pe_v1[c] + 1e-5f);
            float sh = (pe_b1[c] - pe_m1[c]) * s + pe_be1[c];
            float d  = px * pe_w1[c * 3 + 0] + py * pe_w1[c * 3 + 1] + pz * pe_w1[c * 3 + 2];
            PS[wave][lane * 4 + c] = fmaxf(d * s + sh, 0.f);
        }
    }

    // lane = channel params for pos_enc layer 2
    float w20 = pe_w2[lane * 3 + 0], w21 = pe_w2[lane * 3 + 1], w22 = pe_w2[lane * 3 + 2];
    float s2  = pe_g2[lane] * rsqrtf(pe_v2[lane] + 1e-5f);
    float sh2 = (pe_b2[lane] - pe_m2[lane]) * s2 + pe_be2[lane];

    // q for the 4 points (lane = channel)
    float qreg[4];
    #pragma unroll
    for (int pt = 0; pt < 4; pt++)
        qreg[pt] = q_ws[(size_t)(n0 + pt) * MID + lane];

    // D-layout folded BN params for mlp_gamma (channel o = nt*16 + l15)
    float gs1[4], gh1[4], gs2[4], gh2[4];
    #pragma unroll
    for (int nt = 0; nt < 4; nt++) {
        int o = nt * 16 + l15;
        gs1[nt] = ga_g1[o] * rsqrtf(ga_v1[o] + 1e-5f);
        gh1[nt] = (ga_b1[o] - ga_m1[o]) * gs1[nt] + ga_be1[o];
        gs2[nt] = ga_g2[o] * rsqrtf(ga_v2[o] + 1e-5f);
        gh2[nt] = (ga_b2[o] - ga_m2[o]) * gs2[nt] + ga_be2[o];
    }

    // register-resident B fragments for both mlp_gamma layers
    short8 B1[2][4], B2[2][4];
    #pragma unroll
    for (int ks = 0; ks < 2; ks++)
        #pragma unroll
        for (int nt = 0; nt < 4; nt++) {
            B1[ks][nt] = load_cvt8(ga_w1 + (size_t)(nt * 16 + l15) * MID + ks * 32 + quad * 8);
            B2[ks][nt] = load_cvt8(ga_w2 + (size_t)(nt * 16 + l15) * MID + ks * 32 + quad * 8);
        }

    // --- phase 1: gather k, PE2, build w = xk - q + p (lane = channel) ---
    #pragma unroll
    for (int pt = 0; pt < 4; pt++) {
        #pragma unroll
        for (int j = 0; j < KNB; j++) {
            int r = pt * KNB + j;
            int m = JI[wave][r];
            float kg = bf2f(k_bf[(size_t)m * MID + lane]);
            float p10 = PS[wave][r * 4 + 0], p11 = PS[wave][r * 4 + 1], p12 = PS[wave][r * 4 + 2];
            float d = p10 * w20 + p11 * w21 + p12 * w22;
            float p = fmaxf(d * s2 + sh2, 0.f);
            Wb[wave][r * WSTR + lane] = f2bf(kg - qreg[pt] + p);
        }
    }

    // --- phase 2+3 per point: mlp_gamma x2, softmax, weighted sum ---
    #pragma unroll
    for (int pt = 0; pt < 4; pt++) {
        const int rbase = pt * KNB;
        short8 a0 = *(const short8*)&Wb[wave][(rbase + l15) * WSTR + quad * 8];
        short8 a1 = *(const short8*)&Wb[wave][(rbase + l15) * WSTR + 32 + quad * 8];
        #pragma unroll
        for (int nt = 0; nt < 4; nt++) {
            f32x4 c = (f32x4){0.f, 0.f, 0.f, 0.f};
            c = MFMA(a0, B1[0][nt], c);
            c = MFMA(a1, B1[1][nt], c);
            #pragma unroll
            for (int r = 0; r < 4; r++) {
                float v = fmaxf(c[r] * gs1[nt] + gh1[nt], 0.f);
                Wb[wave][(rbase + quad * 4 + r) * WSTR + nt * 16 + l15] = f2bf(v);
            }
        }

        short8 c0 = *(const short8*)&Wb[wave][(rbase + l15) * WSTR + quad * 8];
        short8 c1 = *(const short8*)&Wb[wave][(rbase + l15) * WSTR + 32 + quad * 8];
        float sm[4][4];
        #pragma unroll
        for (int nt = 0; nt < 4; nt++) {
            f32x4 c = (f32x4){0.f, 0.f, 0.f, 0.f};
            c = MFMA(c0, B2[0][nt], c);
            c = MFMA(c1, B2[1][nt], c);
            #pragma unroll
            for (int r = 0; r < 4; r++)
                sm[nt][r] = fmaxf(c[r] * gs2[nt] + gh2[nt], 0.f);
        }

        // softmax over 16 neighbors per channel; write weights back into Wb (bf16)
        #pragma unroll
        for (int nt = 0; nt < 4; nt++) {
            float mx = fmaxf(fmaxf(sm[nt][0], sm[nt][1]), fmaxf(sm[nt][2], sm[nt][3]));
            mx = fmaxf(mx, __shfl_xor(mx, 16));
            mx = fmaxf(mx, __shfl_xor(mx, 32));
            float e[4], s = 0.f;
            #pragma unroll
            for (int r = 0; r < 4; r++) { e[r] = __expf(sm[nt][r] - mx); s += e[r]; }
            s += __shfl_xor(s, 16);
            s += __shfl_xor(s, 32);
            float inv = 1.0f / s;
            #pragma unroll
            for (int r = 0; r < 4; r++)
                Wb[wave][(rbase + quad * 4 + r) * WSTR + nt * 16 + l15] = f2bf(e[r] * inv);
        }

        // weighted sum: re-gather v (L2/L3-warm), recompute p from PS
        float oacc = 0.f;
        #pragma unroll
        for (int j = 0; j < KNB; j++) {
            int r = rbase + j;
            int m = JI[wave][r];
            float vg = bf2f(v_bf[(size_t)m * MID + lane]);
            float p10 = PS[wave][r * 4 + 0], p11 = PS[wave][r * 4 + 1], p12 = PS[wave][r * 4 + 2];
            float d = p10 * w20 + p11 * w21 + p12 * w22;
            float p = fmaxf(d * s2 + sh2, 0.f);
            oacc += (vg + p) * bf2f(Wb[wave][r * WSTR + lane]);
        }
        om_bf[(size_t)(n0 + pt) * MID + lane] = f2bf(oacc);
    }
}

// ---------------------------------------------------------------------------
// Kernel 3: out = out_mid @ w_out.T + feats   [N,64]@[64,256]
// one wave = 32 rows (A-frags resident); block = 128 rows; grid = 512
// ---------------------------------------------------------------------------
__global__ __launch_bounds__(256) void k_out(
    const short* __restrict__ om_bf, const float* __restrict__ w_out,
    const float* __restrict__ feats, float* __restrict__ out)
{
    const int wave = threadIdx.x >> 6, lane = threadIdx.x & 63;
    const int l15 = lane & 15, quad = lane >> 4;
    const int rb0 = (blockIdx.x * 4 + wave) * 32;

    short8 A0[2], A1[2];
    #pragma unroll
    for (int rt = 0; rt < 2; rt++) {
        A0[rt] = *(const short8*)(om_bf + (size_t)(rb0 + rt * 16 + l15) * MID + quad * 8);
        A1[rt] = *(const short8*)(om_bf + (size_t)(rb0 + rt * 16 + l15) * MID + 32 + quad * 8);
    }

    #pragma unroll
    for (int nt = 0; nt < 16; nt++) {
        short8 b0 = load_cvt8(w_out + (size_t)(nt * 16 + l15) * MID + quad * 8);
        short8 b1 = load_cvt8(w_out + (size_t)(nt * 16 + l15) * MID + 32 + quad * 8);
        #pragma unroll
        for (int rt = 0; rt < 2; rt++) {
            f32x4 c = (f32x4){0.f, 0.f, 0.f, 0.f};
            c = MFMA(A0[rt], b0, c);
            c = MFMA(A1[rt], b1, c);
            #pragma unroll
            for (int r = 0; r < 4; r++) {
                size_t off = (size_t)(rb0 + rt * 16 + quad * 4 + r) * INC + nt * 16 + l15;
                out[off] = c[r] + feats[off];
            }
        }
    }
}

extern "C" void kernel_launch(void* const* d_in, const int* in_sizes, int n_in,
                              void* d_out, int out_size, void* d_ws, size_t ws_size,
                              hipStream_t stream)
{
    const float* feats = (const float*)d_in[0];
    const float* pos   = (const float*)d_in[1];
    const int*   idx   = (const int*)d_in[2];
    const float* w_in  = (const float*)d_in[3];
    const float* w_q   = (const float*)d_in[4];
    const float* b_q   = (const float*)d_in[5];
    const float* w_k   = (const float*)d_in[6];
    const float* b_k   = (const float*)d_in[7];
    const float* w_v   = (const float*)d_in[8];
    const float* b_v   = (const float*)d_in[9];
    const float* pe_w1 = (const float*)d_in[10];
    const float* pe_b1 = (const float*)d_in[11];
    const float* pe_g1 = (const float*)d_in[12];
    const float* pe_be1= (const float*)d_in[13];
    const float* pe_m1 = (const float*)d_in[14];
    const float* pe_v1 = (const float*)d_in[15];
    const float* pe_w2 = (const float*)d_in[16];
    const float* pe_b2 = (const float*)d_in[17];
    const float* pe_g2 = (const float*)d_in[18];
    const float* pe_be2= (const float*)d_in[19];
    const float* pe_m2 = (const float*)d_in[20];
    const float* pe_v2 = (const float*)d_in[21];
    const float* ga_w1 = (const float*)d_in[22];
    const float* ga_b1 = (const float*)d_in[23];
    const float* ga_g1 = (const float*)d_in[24];
    const float* ga_be1= (const float*)d_in[25];
    const float* ga_m1 = (const float*)d_in[26];
    const float* ga_v1 = (const float*)d_in[27];
    const float* ga_w2 = (const float*)d_in[28];
    const float* ga_b2 = (const float*)d_in[29];
    const float* ga_g2 = (const float*)d_in[30];
    const float* ga_be2= (const float*)d_in[31];
    const float* ga_m2 = (const float*)d_in[32];
    const float* ga_v2 = (const float*)d_in[33];
    const float* w_out = (const float*)d_in[34];

    char* ws = (char*)d_ws;
    float* q_ws  = (float*)(ws);                            // 16 MB
    short* k_bf  = (short*)(ws + (size_t)16 * 1024 * 1024); // 8 MB
    short* v_bf  = (short*)(ws + (size_t)24 * 1024 * 1024); // 8 MB
    short* om_bf = (short*)(ws + (size_t)32 * 1024 * 1024); // 8 MB

    k_qkv<<<NPTS / 128, 256, 0, stream>>>(feats, w_in, w_q, b_q, w_k, b_k, w_v, b_v,
                                          q_ws, k_bf, v_bf);
    k_attn<<<NPTS / 16, 256, 0, stream>>>(pos, idx, q_ws, k_bf, v_bf,
                                          pe_w1, pe_b1, pe_g1, pe_be1, pe_m1, pe_v1,
                                          pe_w2, pe_b2, pe_g2, pe_be2, pe_m2, pe_v2,
                                          ga_w1, ga_b1, ga_g1, ga_be1, ga_m1, ga_v1,
                                          ga_w2, ga_b2, ga_g2, ga_be2, ga_m2, ga_v2,
                                          om_bf);
    k_out<<<NPTS / 128, 256, 0, stream>>>(om_bf, w_out, feats, (float*)d_out);
}

// Round 3
// 493.504 us; speedup vs baseline: 1.5297x; 1.5297x over previous
//
#include <hip/hip_runtime.h>

#define NPTS 65536
#define INC  256
#define MID  64
#define KNB  16
#define WSTR 72   // padded LDS row stride (shorts)

typedef __attribute__((ext_vector_type(8))) short short8;
typedef __attribute__((ext_vector_type(4))) float f32x4;

#define MFMA(a, b, c) __builtin_amdgcn_mfma_f32_16x16x32_bf16((a), (b), (c), 0, 0, 0)

__device__ inline short f2bf(float f) {
    unsigned int u = __builtin_bit_cast(unsigned int, f);
    unsigned int r = (u + 0x7fffu + ((u >> 16) & 1u)) >> 16;
    return (short)r;
}
__device__ inline float bf2f(unsigned short s) {
    unsigned int u = ((unsigned int)s) << 16;
    return __builtin_bit_cast(float, u);
}
__device__ inline short8 cvtf8(f32x4 a, f32x4 b) {
    short8 r;
    r[0] = f2bf(a[0]); r[1] = f2bf(a[1]); r[2] = f2bf(a[2]); r[3] = f2bf(a[3]);
    r[4] = f2bf(b[0]); r[5] = f2bf(b[1]); r[6] = f2bf(b[2]); r[7] = f2bf(b[3]);
    return r;
}
__device__ inline short8 load_cvt8(const float* __restrict__ p) {
    const f32x4* v = (const f32x4*)p;
    f32x4 a = v[0], b = v[1];
    return cvtf8(a, b);
}

// Fill LDS with bf16 MFMA B-fragments for a [64*nrow16 x 64] row-major matrix.
// frag f covers out-rows nt*16..+16 (nt=f&3 within matrix of 4 tiles) and
// k-cols ks*32..+32.  Entry layout: dst[(f*64 + lane)*8 .. +8].
__device__ inline void fill_frag(short* dst, const float* __restrict__ src, int e) {
    int f = e >> 6, ln = e & 63;
    int nt = f & 3, ks = f >> 2;
    int row = nt * 16 + (ln & 15), col = ks * 32 + (ln >> 4) * 8;
    *(short8*)&dst[(size_t)e * 8] = load_cvt8(src + (size_t)row * MID + col);
}

// ---------------------------------------------------------------------------
// Kernel 1: xx = feats @ w_in.T ; q/k/v = xx @ w_{q,k,v}.T + b
// block = 512 (8 waves); wave = 32 rows (2 tiles); grid = 256
// wq/wk/wv as bf16 fragments in LDS (24 KB); w_in streamed from global/L2
// ---------------------------------------------------------------------------
__global__ __launch_bounds__(512, 4) void k_qkv(
    const float* __restrict__ feats, const float* __restrict__ w_in,
    const float* __restrict__ w_q, const float* __restrict__ b_q,
    const float* __restrict__ w_k, const float* __restrict__ b_k,
    const float* __restrict__ w_v, const float* __restrict__ b_v,
    float* __restrict__ q_out, short* __restrict__ k_out, short* __restrict__ v_out)
{
    __shared__ __align__(16) short BW[3 * 8 * 512];   // 24 KB: wq|wk|wv frags
    __shared__ __align__(16) short XL[8][16 * WSTR];  // 18.4 KB
    const int tid = threadIdx.x;
    const int wave = tid >> 6, lane = tid & 63;
    const int l15 = lane & 15, quad = lane >> 4;

    {
        const float* Ws[3] = {w_q, w_k, w_v};
        #pragma unroll
        for (int rep = 0; rep < 3; rep++) {
            int e = rep * 512 + tid;                  // 1536 entries total
            fill_frag(BW + (size_t)(e >> 9) * 4096, Ws[e >> 9], e & 511);
        }
    }
    __syncthreads();

    const int rb0 = (blockIdx.x * 8 + wave) * 32;
    float bq = b_q[l15 ? 0 : 0]; (void)bq;
    float biasq[4], biask[4], biasv[4];
    #pragma unroll
    for (int nt = 0; nt < 4; nt++) {
        biasq[nt] = b_q[nt * 16 + l15];
        biask[nt] = b_k[nt * 16 + l15];
        biasv[nt] = b_v[nt * 16 + l15];
    }

    #pragma unroll
    for (int rt = 0; rt < 2; rt++) {
        const int rb = rb0 + rt * 16;
        f32x4 acc[4];
        #pragma unroll
        for (int nt = 0; nt < 4; nt++) acc[nt] = (f32x4){0.f, 0.f, 0.f, 0.f};

        const float* arow = feats + (size_t)(rb + l15) * INC + quad * 8;
        #pragma unroll
        for (int ks = 0; ks < 8; ks++) {
            short8 a = load_cvt8(arow + ks * 32);
            #pragma unroll
            for (int nt = 0; nt < 4; nt++) {
                short8 b = load_cvt8(w_in + (size_t)(nt * 16 + l15) * INC + ks * 32 + quad * 8);
                acc[nt] = MFMA(a, b, acc[nt]);
            }
        }
        #pragma unroll
        for (int nt = 0; nt < 4; nt++)
            #pragma unroll
            for (int r = 0; r < 4; r++)
                XL[wave][(quad * 4 + r) * WSTR + nt * 16 + l15] = f2bf(acc[nt][r]);

        short8 a0 = *(const short8*)&XL[wave][l15 * WSTR + quad * 8];
        short8 a1 = *(const short8*)&XL[wave][l15 * WSTR + 32 + quad * 8];

        #pragma unroll
        for (int mtx = 0; mtx < 3; mtx++) {
            const short* base = BW + mtx * 4096;
            #pragma unroll
            for (int nt = 0; nt < 4; nt++) {
                short8 b0 = *(const short8*)&base[(size_t)((0 * 4 + nt) * 64 + lane) * 8];
                short8 b1 = *(const short8*)&base[(size_t)((1 * 4 + nt) * 64 + lane) * 8];
                f32x4 c = (f32x4){0.f, 0.f, 0.f, 0.f};
                c = MFMA(a0, b0, c); c = MFMA(a1, b1, c);
                if (mtx == 0) {
                    #pragma unroll
                    for (int r = 0; r < 4; r++)
                        q_out[(size_t)(rb + quad * 4 + r) * MID + nt * 16 + l15] = c[r] + biasq[nt];
                } else if (mtx == 1) {
                    #pragma unroll
                    for (int r = 0; r < 4; r++)
                        k_out[(size_t)(rb + quad * 4 + r) * MID + nt * 16 + l15] = f2bf(c[r] + biask[nt]);
                } else {
                    #pragma unroll
                    for (int r = 0; r < 4; r++)
                        v_out[(size_t)(rb + quad * 4 + r) * MID + nt * 16 + l15] = f2bf(c[r] + biasv[nt]);
                }
            }
        }
    }
}

// ---------------------------------------------------------------------------
// Kernel 2: per-point attention. block = 512 (8 waves); 1 point/wave per
// iteration x 8 iterations; grid = 1024. mlp_gamma weights in LDS (16 KB).
// ---------------------------------------------------------------------------
__global__ __launch_bounds__(512, 4) void k_attn(
    const float* __restrict__ pos, const int* __restrict__ idx,
    const float* __restrict__ q_ws, const unsigned short* __restrict__ k_bf,
    const unsigned short* __restrict__ v_bf,
    const float* __restrict__ pe_w1, const float* __restrict__ pe_b1,
    const float* __restrict__ pe_g1, const float* __restrict__ pe_be1,
    const float* __restrict__ pe_m1, const float* __restrict__ pe_v1,
    const float* __restrict__ pe_w2, const float* __restrict__ pe_b2,
    const float* __restrict__ pe_g2, const float* __restrict__ pe_be2,
    const float* __restrict__ pe_m2, const float* __restrict__ pe_v2,
    const float* __restrict__ ga_w1, const float* __restrict__ ga_b1,
    const float* __restrict__ ga_g1, const float* __restrict__ ga_be1,
    const float* __restrict__ ga_m1, const float* __restrict__ ga_v1,
    const float* __restrict__ ga_w2, const float* __restrict__ ga_b2,
    const float* __restrict__ ga_g2, const float* __restrict__ ga_be2,
    const float* __restrict__ ga_m2, const float* __restrict__ ga_v2,
    short* __restrict__ om_bf)
{
    __shared__ __align__(16) short BW[2 * 8 * 512];   // 16 KB: ga_w1|ga_w2 frags
    __shared__ __align__(16) short Wb[8][16 * WSTR];  // 18.4 KB activation tiles
    __shared__ float PS[8][16 * 4];                   // PE1 outputs (2 KB)
    __shared__ int   JI[8][16];                       // neighbor indices

    const int tid = threadIdx.x;
    const int wave = tid >> 6, lane = tid & 63;
    const int l15 = lane & 15, quad = lane >> 4;

    {
        const float* Ls[2] = {ga_w1, ga_w2};
        #pragma unroll
        for (int rep = 0; rep < 2; rep++) {
            int e = rep * 512 + tid;                  // 1024 entries total
            fill_frag(BW + (size_t)(e >> 9) * 4096, Ls[e >> 9], e & 511);
        }
    }
    __syncthreads();

    // per-kernel constants (amortized over 8 points)
    float w20 = pe_w2[lane * 3 + 0], w21 = pe_w2[lane * 3 + 1], w22 = pe_w2[lane * 3 + 2];
    float s2  = pe_g2[lane] * rsqrtf(pe_v2[lane] + 1e-5f);
    float sh2 = (pe_b2[lane] - pe_m2[lane]) * s2 + pe_be2[lane];

    float pw[3][4];   // PE1 folded params (used by lanes 0-15; channel c)
    #pragma unroll
    for (int c = 0; c < 3; c++) {
        float s  = pe_g1[c] * rsqrtf(pe_v1[c] + 1e-5f);
        pw[c][0] = pe_w1[c * 3 + 0] * s;
        pw[c][1] = pe_w1[c * 3 + 1] * s;
        pw[c][2] = pe_w1[c * 3 + 2] * s;
        pw[c][3] = (pe_b1[c] - pe_m1[c]) * s + pe_be1[c];
    }

    float gs1[4], gh1[4], gs2[4], gh2[4];
    #pragma unroll
    for (int nt = 0; nt < 4; nt++) {
        int o = nt * 16 + l15;
        gs1[nt] = ga_g1[o] * rsqrtf(ga_v1[o] + 1e-5f);
        gh1[nt] = (ga_b1[o] - ga_m1[o]) * gs1[nt] + ga_be1[o];
        gs2[nt] = ga_g2[o] * rsqrtf(ga_v2[o] + 1e-5f);
        gh2[nt] = (ga_b2[o] - ga_m2[o]) * gs2[nt] + ga_be2[o];
    }

    #pragma unroll 1
    for (int it = 0; it < 8; it++) {
        const int n = blockIdx.x * 64 + it * 8 + wave;

        // stage idx + PE1 per neighbor (lanes 0-15)
        if (lane < 16) {
            int m = idx[(size_t)n * KNB + lane];
            JI[wave][lane] = m;
            float px = pos[(size_t)m * 3 + 0];
            float py = pos[(size_t)m * 3 + 1];
            float pz = pos[(size_t)m * 3 + 2];
            #pragma unroll
            for (int c = 0; c < 3; c++)
                PS[wave][lane * 4 + c] =
                    fmaxf(px * pw[c][0] + py * pw[c][1] + pz * pw[c][2] + pw[c][3], 0.f);
        }

        float qv = q_ws[(size_t)n * MID + lane];

        // batch all gathers so loads stay in flight
        int mj[KNB];
        #pragma unroll
        for (int j = 0; j < KNB; j++) mj[j] = JI[wave][j];
        unsigned short kr[KNB], vr[KNB];
        #pragma unroll
        for (int j = 0; j < KNB; j++) kr[j] = k_bf[(size_t)mj[j] * MID + lane];
        #pragma unroll
        for (int j = 0; j < KNB; j++) vr[j] = v_bf[(size_t)mj[j] * MID + lane];

        // build w = xk - q + p  ->  Wb ;  xvp = v + p  -> regs
        float xvp[KNB];
        #pragma unroll
        for (int j = 0; j < KNB; j++) {
            float p10 = PS[wave][j * 4 + 0], p11 = PS[wave][j * 4 + 1], p12 = PS[wave][j * 4 + 2];
            float p = fmaxf(p10 * w20 + p11 * w21 + p12 * w22 + sh2 * 1.0f
                            + (s2 - 1.0f) * (p10 * w20 + p11 * w21 + p12 * w22), 0.f);
            // note: p = relu((d)*s2 + sh2) computed directly below instead
            float d = p10 * w20 + p11 * w21 + p12 * w22;
            p = fmaxf(d * s2 + sh2, 0.f);
            Wb[wave][j * WSTR + lane] = f2bf(bf2f(kr[j]) - qv + p);
            xvp[j] = bf2f(vr[j]) + p;
        }

        // mlp_gamma layer 1
        short8 a0 = *(const short8*)&Wb[wave][l15 * WSTR + quad * 8];
        short8 a1 = *(const short8*)&Wb[wave][l15 * WSTR + 32 + quad * 8];
        #pragma unroll
        for (int nt = 0; nt < 4; nt++) {
            short8 b0 = *(const short8*)&BW[(size_t)((0 * 4 + nt) * 64 + lane) * 8];
            short8 b1 = *(const short8*)&BW[(size_t)((1 * 4 + nt) * 64 + lane) * 8];
            f32x4 c = (f32x4){0.f, 0.f, 0.f, 0.f};
            c = MFMA(a0, b0, c); c = MFMA(a1, b1, c);
            #pragma unroll
            for (int r = 0; r < 4; r++)
                Wb[wave][(quad * 4 + r) * WSTR + nt * 16 + l15] =
                    f2bf(fmaxf(c[r] * gs1[nt] + gh1[nt], 0.f));
        }

        // mlp_gamma layer 2
        short8 c0 = *(const short8*)&Wb[wave][l15 * WSTR + quad * 8];
        short8 c1 = *(const short8*)&Wb[wave][l15 * WSTR + 32 + quad * 8];
        float sm[4][4];
        #pragma unroll
        for (int nt = 0; nt < 4; nt++) {
            short8 b0 = *(const short8*)&BW[4096 + (size_t)((0 * 4 + nt) * 64 + lane) * 8];
            short8 b1 = *(const short8*)&BW[4096 + (size_t)((1 * 4 + nt) * 64 + lane) * 8];
            f32x4 c = (f32x4){0.f, 0.f, 0.f, 0.f};
            c = MFMA(c0, b0, c); c = MFMA(c1, b1, c);
            #pragma unroll
            for (int r = 0; r < 4; r++)
                sm[nt][r] = fmaxf(c[r] * gs2[nt] + gh2[nt], 0.f);
        }

        // softmax over 16 neighbors per channel; weights back into Wb
        #pragma unroll
        for (int nt = 0; nt < 4; nt++) {
            float mx = fmaxf(fmaxf(sm[nt][0], sm[nt][1]), fmaxf(sm[nt][2], sm[nt][3]));
            mx = fmaxf(mx, __shfl_xor(mx, 16));
            mx = fmaxf(mx, __shfl_xor(mx, 32));
            float e[4], s = 0.f;
            #pragma unroll
            for (int r = 0; r < 4; r++) { e[r] = __expf(sm[nt][r] - mx); s += e[r]; }
            s += __shfl_xor(s, 16);
            s += __shfl_xor(s, 32);
            float inv = 1.0f / s;
            #pragma unroll
            for (int r = 0; r < 4; r++)
                Wb[wave][(quad * 4 + r) * WSTR + nt * 16 + l15] = f2bf(e[r] * inv);
        }

        // weighted sum
        float oacc = 0.f;
        #pragma unroll
        for (int j = 0; j < KNB; j++)
            oacc += xvp[j] * bf2f((unsigned short)Wb[wave][j * WSTR + lane]);
        om_bf[(size_t)n * MID + lane] = f2bf(oacc);
    }
}

// ---------------------------------------------------------------------------
// Kernel 3: out = out_mid @ w_out.T + feats   [N,64]@[64,256]
// block = 512 (8 waves); wave = 32 rows; grid = 256. w_out in LDS (32 KB).
// ---------------------------------------------------------------------------
__global__ __launch_bounds__(512, 4) void k_out(
    const short* __restrict__ om_bf, const float* __restrict__ w_out,
    const float* __restrict__ feats, float* __restrict__ out)
{
    __shared__ __align__(16) short BW[32 * 512];      // 32 KB: w_out frags (nt 0..15, ks 0..1)
    const int tid = threadIdx.x;
    const int wave = tid >> 6, lane = tid & 63;
    const int l15 = lane & 15, quad = lane >> 4;

    // 2048 entries: f = e>>6 (0..31): nt = f>>1, ks = f&1
    #pragma unroll
    for (int rep = 0; rep < 4; rep++) {
        int e = rep * 512 + tid;
        int f = e >> 6, ln = e & 63;
        int nt = f >> 1, ks = f & 1;
        int row = nt * 16 + (ln & 15), col = ks * 32 + (ln >> 4) * 8;
        *(short8*)&BW[(size_t)e * 8] = load_cvt8(w_out + (size_t)row * MID + col);
    }
    __syncthreads();

    const int rb0 = (blockIdx.x * 8 + wave) * 32;
    short8 A0[2], A1[2];
    #pragma unroll
    for (int rt = 0; rt < 2; rt++) {
        A0[rt] = *(const short8*)(om_bf + (size_t)(rb0 + rt * 16 + l15) * MID + quad * 8);
        A1[rt] = *(const short8*)(om_bf + (size_t)(rb0 + rt * 16 + l15) * MID + 32 + quad * 8);
    }

    #pragma unroll 2
    for (int nt = 0; nt < 16; nt++) {
        short8 b0 = *(const short8*)&BW[(size_t)((nt * 2 + 0) * 64 + lane) * 8];
        short8 b1 = *(const short8*)&BW[(size_t)((nt * 2 + 1) * 64 + lane) * 8];
        #pragma unroll
        for (int rt = 0; rt < 2; rt++) {
            f32x4 c = (f32x4){0.f, 0.f, 0.f, 0.f};
            c = MFMA(A0[rt], b0, c);
            c = MFMA(A1[rt], b1, c);
            #pragma unroll
            for (int r = 0; r < 4; r++) {
                size_t off = (size_t)(rb0 + rt * 16 + quad * 4 + r) * INC + nt * 16 + l15;
                out[off] = c[r] + feats[off];
            }
        }
    }
}

extern "C" void kernel_launch(void* const* d_in, const int* in_sizes, int n_in,
                              void* d_out, int out_size, void* d_ws, size_t ws_size,
                              hipStream_t stream)
{
    const float* feats = (const float*)d_in[0];
    const float* pos   = (const float*)d_in[1];
    const int*   idx   = (const int*)d_in[2];
    const float* w_in  = (const float*)d_in[3];
    const float* w_q   = (const float*)d_in[4];
    const float* b_q   = (const float*)d_in[5];
    const float* w_k   = (const float*)d_in[6];
    const float* b_k   = (const float*)d_in[7];
    const float* w_v   = (const float*)d_in[8];
    const float* b_v   = (const float*)d_in[9];
    const float* pe_w1 = (const float*)d_in[10];
    const float* pe_b1 = (const float*)d_in[11];
    const float* pe_g1 = (const float*)d_in[12];
    const float* pe_be1= (const float*)d_in[13];
    const float* pe_m1 = (const float*)d_in[14];
    const float* pe_v1 = (const float*)d_in[15];
    const float* pe_w2 = (const float*)d_in[16];
    const float* pe_b2 = (const float*)d_in[17];
    const float* pe_g2 = (const float*)d_in[18];
    const float* pe_be2= (const float*)d_in[19];
    const float* pe_m2 = (const float*)d_in[20];
    const float* pe_v2 = (const float*)d_in[21];
    const float* ga_w1 = (const float*)d_in[22];
    const float* ga_b1 = (const float*)d_in[23];
    const float* ga_g1 = (const float*)d_in[24];
    const float* ga_be1= (const float*)d_in[25];
    const float* ga_m1 = (const float*)d_in[26];
    const float* ga_v1 = (const float*)d_in[27];
    const float* ga_w2 = (const float*)d_in[28];
    const float* ga_b2 = (const float*)d_in[29];
    const float* ga_g2 = (const float*)d_in[30];
    const float* ga_be2= (const float*)d_in[31];
    const float* ga_m2 = (const float*)d_in[32];
    const float* ga_v2 = (const float*)d_in[33];
    const float* w_out = (const float*)d_in[34];

    char* ws = (char*)d_ws;
    float* q_ws  = (float*)(ws);                            // 16 MB
    short* k_bf  = (short*)(ws + (size_t)16 * 1024 * 1024); // 8 MB
    short* v_bf  = (short*)(ws + (size_t)24 * 1024 * 1024); // 8 MB
    short* om_bf = (short*)(ws + (size_t)32 * 1024 * 1024); // 8 MB

    k_qkv<<<NPTS / 256, 512, 0, stream>>>(feats, w_in, w_q, b_q, w_k, b_k, w_v, b_v,
                                          q_ws, k_bf, v_bf);
    k_attn<<<NPTS / 64, 512, 0, stream>>>(pos, idx, q_ws,
                                          (const unsigned short*)k_bf, (const unsigned short*)v_bf,
                                          pe_w1, pe_b1, pe_g1, pe_be1, pe_m1, pe_v1,
                                          pe_w2, pe_b2, pe_g2, pe_be2, pe_m2, pe_v2,
                                          ga_w1, ga_b1, ga_g1, ga_be1, ga_m1, ga_v1,
                                          ga_w2, ga_b2, ga_g2, ga_be2, ga_m2, ga_v2,
                                          om_bf);
    k_out<<<NPTS / 256, 512, 0, stream>>>(om_bf, w_out, feats, (float*)d_out);
}